// Round 2
// baseline (18540.958 us; speedup 1.0000x reference)
//
#include <hip/hip_runtime.h>
#include <hip/hip_bf16.h>
#include <cstdint>
#include <cstddef>

#define B_ 64
#define T_ 1024
#define H_ 256

typedef __attribute__((ext_vector_type(8))) unsigned short ushort8;

__device__ __forceinline__ float sigm(float x) { return 1.f / (1.f + __expf(-x)); }
__device__ __forceinline__ float tanh_fast(float x) {
  float e = __expf(2.f * x);
  return 1.f - 2.f / (e + 1.f);
}

// Permute columns into gate-interleaved order: dst[k][hc*4+g] = src[k][g*256+hc]
__global__ __launch_bounds__(256) void permute_cols(const float* __restrict__ src,
                                                    float* __restrict__ dst, int K) {
  int idx = blockIdx.x * 256 + threadIdx.x;
  if (idx >= K * 1024) return;
  int n = idx & 1023;
  size_t k = (size_t)(idx >> 10);
  dst[idx] = src[(k << 10) + ((size_t)(n & 3) << 8) + (n >> 2)];
}

// out[i] = bd (init for fused dense-head atomics); also diag mode
__global__ __launch_bounds__(256) void init_out(float* __restrict__ out,
                                                const float* __restrict__ bd, int n) {
  int i = blockIdx.x * 256 + threadIdx.x;
  if (i < n) out[i] = bd[0];
}

__global__ __launch_bounds__(256) void diag_out(float* __restrict__ out, int n, float v) {
  int i = blockIdx.x * 256 + threadIdx.x;
  if (i < n) out[i] = (i == 0) ? v : 0.f;
}

// xp[dir][b][sl][1024] = A[b][t(sl)][:] @ Wperm[dir] + biasperm[dir]
// sl = scan-order index within chunk: fwd t = s0+sl ; bwd t = 1023-(s0+sl)
// grid: ((Tc/64)*16, B, 2), block 256. A_BF16: A is bf16 (h0 stored compact).
template <int A_BF16>
__global__ __launch_bounds__(256) void proj_gemm_chunk(
    const void* __restrict__ Av,
    const float* __restrict__ Wf, const float* __restrict__ Wb,
    const float* __restrict__ bf_, const float* __restrict__ bb_,
    float* __restrict__ xp, int K, int s0, int Tc) {
  const int dir = blockIdx.z;
  const float* W = dir ? Wb : Wf;
  const float* bs = dir ? bb_ : bf_;
  const int b = blockIdx.y;
  const int tt = blockIdx.x >> 4;
  const int nt = blockIdx.x & 15;
  const int t0 = (dir ? (T_ - s0 - Tc) : s0) + (tt << 6);
  const int n0 = nt << 6;
  const int tid = threadIdx.x;
  const int tx = tid & 15, ty = tid >> 4;

  __shared__ __align__(16) float As[64][36];
  __shared__ __align__(16) float Bs[32][68];

  float acc[4][4];
#pragma unroll
  for (int i = 0; i < 4; i++)
#pragma unroll
    for (int j = 0; j < 4; j++) acc[i][j] = 0.f;

  const int r = tid >> 2;           // A row this thread stages
  const int kc = (tid & 3) * 8;     // k offset (8 elements)

  for (int k0 = 0; k0 < K; k0 += 32) {
    if (A_BF16) {
      const unsigned short* Ar = (const unsigned short*)Av +
          ((size_t)b * T_ + t0 + r) * K + k0 + kc;
      ushort8 v = *(const ushort8*)Ar;
#pragma unroll
      for (int j = 0; j < 8; j++)
        As[r][kc + j] = __uint_as_float(((unsigned)v[j]) << 16);
    } else {
      const float* Ar = (const float*)Av + ((size_t)b * T_ + t0 + r) * K + k0 + kc;
      *(float4*)&As[r][kc] = *(const float4*)Ar;
      *(float4*)&As[r][kc + 4] = *(const float4*)(Ar + 4);
    }
#pragma unroll
    for (int u = 0; u < 2; u++) {
      int f = tid * 2 + u;
      int kk = f >> 4;
      int cc = f & 15;
      *(float4*)&Bs[kk][cc * 4] =
          *(const float4*)(W + (size_t)(k0 + kk) * 1024 + n0 + cc * 4);
    }
    __syncthreads();
#pragma unroll
    for (int kk = 0; kk < 32; ++kk) {
      float4 bq = *(const float4*)&Bs[kk][tx * 4];
      float a0 = As[ty * 4 + 0][kk];
      float a1 = As[ty * 4 + 1][kk];
      float a2 = As[ty * 4 + 2][kk];
      float a3 = As[ty * 4 + 3][kk];
      acc[0][0] += a0 * bq.x; acc[0][1] += a0 * bq.y; acc[0][2] += a0 * bq.z; acc[0][3] += a0 * bq.w;
      acc[1][0] += a1 * bq.x; acc[1][1] += a1 * bq.y; acc[1][2] += a1 * bq.z; acc[1][3] += a1 * bq.w;
      acc[2][0] += a2 * bq.x; acc[2][1] += a2 * bq.y; acc[2][2] += a2 * bq.z; acc[2][3] += a2 * bq.w;
      acc[3][0] += a3 * bq.x; acc[3][1] += a3 * bq.y; acc[3][2] += a3 * bq.z; acc[3][3] += a3 * bq.w;
    }
    __syncthreads();
  }
  float4 bv = *(const float4*)(bs + n0 + tx * 4);
#pragma unroll
  for (int i = 0; i < 4; i++) {
    int t = t0 + ty * 4 + i;
    int sl = dir ? (T_ - 1 - t - s0) : (t - s0);
    float4 o;
    o.x = acc[i][0] + bv.x;
    o.y = acc[i][1] + bv.y;
    o.z = acc[i][2] + bv.z;
    o.w = acc[i][3] + bv.w;
    *(float4*)(xp + ((((size_t)dir * B_ + b) * Tc + sl) << 10) + n0 + tx * 4) = o;
  }
}

// One WG per (batch-pair, direction); 256 threads = one h-column each.
// Processes steps s in [s0, s0+Tc). State carried via `carry` buffer:
// carry[((dir*2 + {0:h,1:c})*B + b)*256 + col].
// WRITE_H: layer0 -> write h into hout ([B][T][512], f32 or bf16 per H_BF16).
// else   : layer1 -> fused dense head: atomicAdd(out[b*T+t], sum(h*Wd_half)).
template <int WRITE_H, int H_BF16>
__global__ __launch_bounds__(256) void lstm_scan_chunk(
    const float* __restrict__ xp,
    const float* __restrict__ Up_f, const float* __restrict__ Up_b,
    float* __restrict__ carry, int s0, int Tc,
    void* __restrict__ hout,
    const float* __restrict__ Wd, float* __restrict__ out) {
  const int dir = blockIdx.x & 1;
  const int bp = blockIdx.x >> 1;
  const int b0 = bp * 2, b1 = b0 + 1;
  const int tid = threadIdx.x;
  const float* Up = dir ? Up_b : Up_f;

  __shared__ __align__(16) float h_sm[2][256];
  __shared__ float red_sm[2][4];

  float c0, c1, h0v, h1v;
  if (s0 == 0) {
    h_sm[0][tid] = 0.f;
    h_sm[1][tid] = 0.f;
    c0 = 0.f;
    c1 = 0.f;
  } else {
    h_sm[0][tid] = carry[((size_t)(dir * 2 + 0) * B_ + b0) * 256 + tid];
    h_sm[1][tid] = carry[((size_t)(dir * 2 + 0) * B_ + b1) * 256 + tid];
    c0 = carry[((size_t)(dir * 2 + 1) * B_ + b0) * 256 + tid];
    c1 = carry[((size_t)(dir * 2 + 1) * B_ + b1) * 256 + tid];
  }
  h0v = h_sm[0][tid];
  h1v = h_sm[1][tid];
  float wd0 = 0.f;
  if (!WRITE_H) wd0 = Wd[dir * 256 + tid];
  __syncthreads();

  const float* xp0 = xp + ((((size_t)dir * B_ + b0) * Tc) << 10) + tid * 4;
  const float* xp1 = xp + ((((size_t)dir * B_ + b1) * Tc) << 10) + tid * 4;

  for (int sl = 0; sl < Tc; ++sl) {
    const int s = s0 + sl;
    const int t = dir ? (T_ - 1 - s) : s;
    float4 z0 = *(const float4*)(xp0 + ((size_t)sl << 10));
    float4 z1 = *(const float4*)(xp1 + ((size_t)sl << 10));
    float4 r0 = make_float4(0.f, 0.f, 0.f, 0.f), r1 = r0;
#pragma unroll 4
    for (int k = 0; k < 256; k += 4) {
      float4 hv0 = *(const float4*)&h_sm[0][k];
      float4 hv1 = *(const float4*)&h_sm[1][k];
      float a0q[4] = {hv0.x, hv0.y, hv0.z, hv0.w};
      float a1q[4] = {hv1.x, hv1.y, hv1.z, hv1.w};
#pragma unroll
      for (int q = 0; q < 4; ++q) {
        float4 u = *(const float4*)(Up + ((size_t)(k + q) << 10) + (tid << 2));
        r0.x += a0q[q] * u.x; r0.y += a0q[q] * u.y; r0.z += a0q[q] * u.z; r0.w += a0q[q] * u.w;
        r1.x += a1q[q] * u.x; r1.y += a1q[q] * u.y; r1.z += a1q[q] * u.z; r1.w += a1q[q] * u.w;
      }
    }
    z0.x += r0.x; z0.y += r0.y; z0.z += r0.z; z0.w += r0.w;
    z1.x += r1.x; z1.y += r1.y; z1.z += r1.z; z1.w += r1.w;
    float i0 = sigm(z0.x), f0 = sigm(z0.y), g0 = tanh_fast(z0.z), o0 = sigm(z0.w);
    float i1 = sigm(z1.x), f1 = sigm(z1.y), g1 = tanh_fast(z1.z), o1 = sigm(z1.w);
    c0 = f0 * c0 + i0 * g0;
    c1 = f1 * c1 + i1 * g1;
    h0v = o0 * tanh_fast(c0);
    h1v = o1 * tanh_fast(c1);
    __syncthreads();
    h_sm[0][tid] = h0v;
    h_sm[1][tid] = h1v;
    if (WRITE_H) {
      size_t o0i = ((((size_t)b0 << 10) + t) << 9) + dir * 256 + tid;
      size_t o1i = ((((size_t)b1 << 10) + t) << 9) + dir * 256 + tid;
      if (H_BF16) {
        ((__hip_bfloat16*)hout)[o0i] = __float2bfloat16(h0v);
        ((__hip_bfloat16*)hout)[o1i] = __float2bfloat16(h1v);
      } else {
        ((float*)hout)[o0i] = h0v;
        ((float*)hout)[o1i] = h1v;
      }
    } else {
      float v0 = h0v * wd0, v1 = h1v * wd0;
#pragma unroll
      for (int o = 32; o > 0; o >>= 1) {
        v0 += __shfl_down(v0, o);
        v1 += __shfl_down(v1, o);
      }
      if ((tid & 63) == 0) {
        red_sm[0][tid >> 6] = v0;
        red_sm[1][tid >> 6] = v1;
      }
    }
    __syncthreads();
    if (!WRITE_H) {
      if (tid == 0)
        atomicAdd(out + ((size_t)b0 << 10) + t,
                  (red_sm[0][0] + red_sm[0][1]) + (red_sm[0][2] + red_sm[0][3]));
      if (tid == 1)
        atomicAdd(out + ((size_t)b1 << 10) + t,
                  (red_sm[1][0] + red_sm[1][1]) + (red_sm[1][2] + red_sm[1][3]));
    }
  }
  carry[((size_t)(dir * 2 + 0) * B_ + b0) * 256 + tid] = h0v;
  carry[((size_t)(dir * 2 + 0) * B_ + b1) * 256 + tid] = h1v;
  carry[((size_t)(dir * 2 + 1) * B_ + b0) * 256 + tid] = c0;
  carry[((size_t)(dir * 2 + 1) * B_ + b1) * 256 + tid] = c1;
}

extern "C" void kernel_launch(void* const* d_in, const int* in_sizes, int n_in,
                              void* d_out, int out_size, void* d_ws, size_t ws_size,
                              hipStream_t stream) {
  const float* x   = (const float*)d_in[0];
  const float* W0f = (const float*)d_in[1];
  const float* U0f = (const float*)d_in[2];
  const float* b0f = (const float*)d_in[3];
  const float* W0b = (const float*)d_in[4];
  const float* U0b = (const float*)d_in[5];
  const float* b0b = (const float*)d_in[6];
  const float* W1f = (const float*)d_in[7];
  const float* U1f = (const float*)d_in[8];
  const float* b1f = (const float*)d_in[9];
  const float* W1b = (const float*)d_in[10];
  const float* U1b = (const float*)d_in[11];
  const float* b1b = (const float*)d_in[12];
  const float* Wd  = (const float*)d_in[13];
  const float* bd  = (const float*)d_in[14];
  float* out = (float*)d_out;
  char* ws = (char*)d_ws;

  const size_t H0F_BYTES = (size_t)B_ * T_ * 512 * 4;   // 128 MiB (f32)
  const size_t UP_BYTES  = (size_t)256 * 1024 * 4;      // 1 MiB
  const size_t WP0_BYTES = (size_t)64 * 1024 * 4;       // 256 KiB
  const size_t WP1_BYTES = (size_t)512 * 1024 * 4;      // 2 MiB
  const size_t BP_BYTES  = 1024 * 4;
  const size_t REPACK = 4 * UP_BYTES + 2 * WP0_BYTES + 2 * WP1_BYTES + 4 * BP_BYTES;
  const size_t CARRY_BYTES = (size_t)2 * 2 * B_ * 256 * 4;  // 512 KiB

  // tier selection: prefer f32 h0, larger Tc
  int h0bf16 = -1, Tc = 0;
  for (int prec = 0; prec < 2 && h0bf16 < 0; ++prec) {
    size_t h0b = prec ? (H0F_BYTES / 2) : H0F_BYTES;
    for (int tc = 128; tc >= 64; tc >>= 1) {
      size_t xpb = (size_t)2 * B_ * tc * 1024 * 4;
      if (h0b + REPACK + CARRY_BYTES + xpb <= ws_size) {
        h0bf16 = prec;
        Tc = tc;
        break;
      }
    }
  }
  if (h0bf16 < 0) {
    // nothing fits: fail visibly, encode ws_size (MiB) in out[0] for diagnosis
    float v = 1000.f + (float)(ws_size >> 20);
    diag_out<<<(out_size + 255) / 256, 256, 0, stream>>>(out, out_size, v);
    return;
  }

  size_t h0b = h0bf16 ? (H0F_BYTES / 2) : H0F_BYTES;
  size_t off = 0;
  void*  h0   = (void*)(ws + off); off += h0b;
  float* Up00 = (float*)(ws + off); off += UP_BYTES;
  float* Up01 = (float*)(ws + off); off += UP_BYTES;
  float* Up10 = (float*)(ws + off); off += UP_BYTES;
  float* Up11 = (float*)(ws + off); off += UP_BYTES;
  float* Wp0f = (float*)(ws + off); off += WP0_BYTES;
  float* Wp0b = (float*)(ws + off); off += WP0_BYTES;
  float* Wp1f = (float*)(ws + off); off += WP1_BYTES;
  float* Wp1b = (float*)(ws + off); off += WP1_BYTES;
  float* bp0f = (float*)(ws + off); off += BP_BYTES;
  float* bp0b = (float*)(ws + off); off += BP_BYTES;
  float* bp1f = (float*)(ws + off); off += BP_BYTES;
  float* bp1b = (float*)(ws + off); off += BP_BYTES;
  float* carry = (float*)(ws + off); off += CARRY_BYTES;
  float* xpc  = (float*)(ws + off);

  // --- weight/bias repacking (gate-interleaved column order) ---
  permute_cols<<<1024, 256, 0, stream>>>(U0f, Up00, 256);
  permute_cols<<<1024, 256, 0, stream>>>(U0b, Up01, 256);
  permute_cols<<<1024, 256, 0, stream>>>(U1f, Up10, 256);
  permute_cols<<<1024, 256, 0, stream>>>(U1b, Up11, 256);
  permute_cols<<<256, 256, 0, stream>>>(W0f, Wp0f, 64);
  permute_cols<<<256, 256, 0, stream>>>(W0b, Wp0b, 64);
  permute_cols<<<2048, 256, 0, stream>>>(W1f, Wp1f, 512);
  permute_cols<<<2048, 256, 0, stream>>>(W1b, Wp1b, 512);
  permute_cols<<<4, 256, 0, stream>>>(b0f, bp0f, 1);
  permute_cols<<<4, 256, 0, stream>>>(b0b, bp0b, 1);
  permute_cols<<<4, 256, 0, stream>>>(b1f, bp1f, 1);
  permute_cols<<<4, 256, 0, stream>>>(b1b, bp1b, 1);

  const int nch = T_ / Tc;
  const dim3 ggrid((Tc / 64) * 16, B_, 2);

  // ---- layer 0: x -> h0 ----
  for (int ci = 0; ci < nch; ++ci) {
    int s0c = ci * Tc;
    proj_gemm_chunk<0><<<ggrid, 256, 0, stream>>>(x, Wp0f, Wp0b, bp0f, bp0b,
                                                  xpc, 64, s0c, Tc);
    if (h0bf16)
      lstm_scan_chunk<1, 1><<<64, 256, 0, stream>>>(xpc, Up00, Up01, carry, s0c, Tc,
                                                    h0, nullptr, nullptr);
    else
      lstm_scan_chunk<1, 0><<<64, 256, 0, stream>>>(xpc, Up00, Up01, carry, s0c, Tc,
                                                    h0, nullptr, nullptr);
  }

  // ---- layer 1: h0 -> out (fused dense head) ----
  init_out<<<(out_size + 255) / 256, 256, 0, stream>>>(out, bd, out_size);
  for (int ci = 0; ci < nch; ++ci) {
    int s0c = ci * Tc;
    if (h0bf16)
      proj_gemm_chunk<1><<<ggrid, 256, 0, stream>>>(h0, Wp1f, Wp1b, bp1f, bp1b,
                                                    xpc, 512, s0c, Tc);
    else
      proj_gemm_chunk<0><<<ggrid, 256, 0, stream>>>(h0, Wp1f, Wp1b, bp1f, bp1b,
                                                    xpc, 512, s0c, Tc);
    lstm_scan_chunk<0, 0><<<64, 256, 0, stream>>>(xpc, Up10, Up11, carry, s0c, Tc,
                                                  nullptr, Wd, out);
  }
}

// Round 3
// 9545.129 us; speedup vs baseline: 1.9425x; 1.9425x over previous
//
#include <hip/hip_runtime.h>
#include <hip/hip_bf16.h>
#include <cstdint>
#include <cstddef>

#define B_ 64
#define T_ 1024

typedef _Float16 half_t;
typedef __attribute__((ext_vector_type(2))) _Float16 half2_t;
typedef __attribute__((ext_vector_type(8))) unsigned short ushort8;

__device__ __forceinline__ float sigm(float x) { return 1.f / (1.f + __expf(-x)); }
__device__ __forceinline__ float tanh_fast(float x) {
  float e = __expf(2.f * x);
  return 1.f - 2.f / (e + 1.f);
}

__device__ __forceinline__ float dot2h(unsigned u, unsigned h, float acc) {
#if __has_builtin(__builtin_amdgcn_fdot2)
  return __builtin_amdgcn_fdot2(__builtin_bit_cast(half2_t, u),
                                __builtin_bit_cast(half2_t, h), acc, false);
#else
  half2_t a = __builtin_bit_cast(half2_t, u);
  half2_t b = __builtin_bit_cast(half2_t, h);
  return acc + (float)a.x * (float)b.x + (float)a.y * (float)b.y;
#endif
}

// Permute columns into gate-interleaved order: dst[k][hc*4+g] = src[k][g*256+hc]
__global__ __launch_bounds__(256) void permute_cols(const float* __restrict__ src,
                                                    float* __restrict__ dst, int K) {
  int idx = blockIdx.x * 256 + threadIdx.x;
  if (idx >= K * 1024) return;
  int n = idx & 1023;
  size_t k = (size_t)(idx >> 10);
  dst[idx] = src[(k << 10) + ((size_t)(n & 3) << 8) + (n >> 2)];
}

// U [256][1024] (gate-blocked cols) -> Upk [128][1024] uint, n'=hc*4+g,
// uint = (f16 U[2k2][n'], f16 U[2k2+1][n']) packed lo|hi.
__global__ __launch_bounds__(256) void pack_u_f16(const float* __restrict__ src,
                                                  unsigned* __restrict__ dst) {
  int idx = blockIdx.x * 256 + threadIdx.x;  // 128*1024 total
  int n = idx & 1023;
  int k2 = idx >> 10;
  int sc = ((n & 3) << 8) + (n >> 2);
  float a = src[((size_t)(2 * k2) << 10) + sc];
  float b = src[((size_t)(2 * k2 + 1) << 10) + sc];
  half2_t p;
  p.x = (half_t)a;
  p.y = (half_t)b;
  dst[idx] = __builtin_bit_cast(unsigned, p);
}

__global__ __launch_bounds__(256) void init_out(float* __restrict__ out,
                                                const float* __restrict__ bd, int n) {
  int i = blockIdx.x * 256 + threadIdx.x;
  if (i < n) out[i] = bd[0];
}

__global__ __launch_bounds__(256) void diag_out(float* __restrict__ out, int n, float v) {
  int i = blockIdx.x * 256 + threadIdx.x;
  if (i < n) out[i] = (i == 0) ? v : 0.f;
}

// xp[dir][b][sl][1024] = A[b][t(sl)][:] @ Wperm[dir] + biasperm[dir]
template <int A_BF16>
__global__ __launch_bounds__(256) void proj_gemm_chunk(
    const void* __restrict__ Av,
    const float* __restrict__ Wf, const float* __restrict__ Wb,
    const float* __restrict__ bf_, const float* __restrict__ bb_,
    float* __restrict__ xp, int K, int s0, int Tc) {
  const int dir = blockIdx.z;
  const float* W = dir ? Wb : Wf;
  const float* bs = dir ? bb_ : bf_;
  const int b = blockIdx.y;
  const int tt = blockIdx.x >> 4;
  const int nt = blockIdx.x & 15;
  const int t0 = (dir ? (T_ - s0 - Tc) : s0) + (tt << 6);
  const int n0 = nt << 6;
  const int tid = threadIdx.x;
  const int tx = tid & 15, ty = tid >> 4;

  __shared__ __align__(16) float As[64][36];
  __shared__ __align__(16) float Bs[32][68];

  float acc[4][4];
#pragma unroll
  for (int i = 0; i < 4; i++)
#pragma unroll
    for (int j = 0; j < 4; j++) acc[i][j] = 0.f;

  const int r = tid >> 2;
  const int kc = (tid & 3) * 8;

  for (int k0 = 0; k0 < K; k0 += 32) {
    if (A_BF16) {
      const unsigned short* Ar = (const unsigned short*)Av +
          ((size_t)b * T_ + t0 + r) * K + k0 + kc;
      ushort8 v = *(const ushort8*)Ar;
#pragma unroll
      for (int jj = 0; jj < 8; jj++)
        As[r][kc + jj] = __uint_as_float(((unsigned)v[jj]) << 16);
    } else {
      const float* Ar = (const float*)Av + ((size_t)b * T_ + t0 + r) * K + k0 + kc;
      *(float4*)&As[r][kc] = *(const float4*)Ar;
      *(float4*)&As[r][kc + 4] = *(const float4*)(Ar + 4);
    }
#pragma unroll
    for (int u = 0; u < 2; u++) {
      int f = tid * 2 + u;
      int kk = f >> 4;
      int cc = f & 15;
      *(float4*)&Bs[kk][cc * 4] =
          *(const float4*)(W + (size_t)(k0 + kk) * 1024 + n0 + cc * 4);
    }
    __syncthreads();
#pragma unroll
    for (int kk = 0; kk < 32; ++kk) {
      float4 bq = *(const float4*)&Bs[kk][tx * 4];
      float a0 = As[ty * 4 + 0][kk];
      float a1 = As[ty * 4 + 1][kk];
      float a2 = As[ty * 4 + 2][kk];
      float a3 = As[ty * 4 + 3][kk];
      acc[0][0] += a0 * bq.x; acc[0][1] += a0 * bq.y; acc[0][2] += a0 * bq.z; acc[0][3] += a0 * bq.w;
      acc[1][0] += a1 * bq.x; acc[1][1] += a1 * bq.y; acc[1][2] += a1 * bq.z; acc[1][3] += a1 * bq.w;
      acc[2][0] += a2 * bq.x; acc[2][1] += a2 * bq.y; acc[2][2] += a2 * bq.z; acc[2][3] += a2 * bq.w;
      acc[3][0] += a3 * bq.x; acc[3][1] += a3 * bq.y; acc[3][2] += a3 * bq.z; acc[3][3] += a3 * bq.w;
    }
    __syncthreads();
  }
  float4 bv = *(const float4*)(bs + n0 + tx * 4);
#pragma unroll
  for (int i = 0; i < 4; i++) {
    int t = t0 + ty * 4 + i;
    int sl = dir ? (T_ - 1 - t - s0) : (t - s0);
    float4 o;
    o.x = acc[i][0] + bv.x;
    o.y = acc[i][1] + bv.y;
    o.z = acc[i][2] + bv.z;
    o.w = acc[i][3] + bv.w;
    *(float4*)(xp + ((((size_t)dir * B_ + b) * Tc + sl) << 10) + n0 + tx * 4) = o;
  }
}

// Scan v2: 128 WGs (one per (b,dir)), 256 threads = one h-col each (4 gate cols).
// U packed f16-pairs [128][1024]; h broadcast via packed-f16 LDS.
template <int WRITE_H, int H_BF16>
__global__ __launch_bounds__(256) void lstm_scan2(
    const float* __restrict__ xp,
    const unsigned* __restrict__ Uf, const unsigned* __restrict__ Ub,
    float* __restrict__ carry, int s0, int Tc,
    void* __restrict__ hout,
    const float* __restrict__ Wd, float* __restrict__ out) {
  const int dir = blockIdx.x & 1;
  const int b = blockIdx.x >> 1;
  const int j = threadIdx.x;
  const unsigned* __restrict__ U = dir ? Ub : Uf;
  const unsigned* __restrict__ Uj = U + (j << 2);

  __shared__ unsigned h_pk[128];
  __shared__ float red[4];

  float c_, h_;
  if (s0 == 0) {
    h_ = 0.f;
    c_ = 0.f;
  } else {
    h_ = carry[((size_t)(dir * 2 + 0) * B_ + b) * 256 + j];
    c_ = carry[((size_t)(dir * 2 + 1) * B_ + b) * 256 + j];
  }
  ((half_t*)h_pk)[j] = (half_t)h_;
  float wdj = 0.f;
  if (!WRITE_H) wdj = Wd[dir * 256 + j];
  __syncthreads();

  const float* __restrict__ xpb =
      xp + ((((size_t)dir * B_ + b) * Tc) << 10) + (j << 2);
  float4 zn = *(const float4*)xpb;

#define LDU(v, k2i) v = *(const uint4*)(Uj + ((size_t)(k2i) << 10))
#define DOTQ(p, hpq)                                   \
  z.x = dot2h(p.x, hpq, z.x);                          \
  z.y = dot2h(p.y, hpq, z.y);                          \
  z.z = dot2h(p.z, hpq, z.z);                          \
  z.w = dot2h(p.w, hpq, z.w)

  for (int sl = 0; sl < Tc; ++sl) {
    const int s = s0 + sl;
    const int t = dir ? (T_ - 1 - s) : s;
    float4 z = zn;
    if (sl + 1 < Tc) zn = *(const float4*)(xpb + ((size_t)(sl + 1) << 10));

    uint4 pa0, pa1, pa2, pa3, pb0, pb1, pb2, pb3;
    LDU(pa0, 0); LDU(pa1, 1); LDU(pa2, 2); LDU(pa3, 3);
    LDU(pb0, 4); LDU(pb1, 5); LDU(pb2, 6); LDU(pb3, 7);
#pragma unroll
    for (int g2 = 0; g2 < 16; ++g2) {
      {
        const int g = 2 * g2;
        uint4 hp = *(const uint4*)&h_pk[g << 2];
        DOTQ(pa0, hp.x);
        DOTQ(pa1, hp.y);
        DOTQ(pa2, hp.z);
        DOTQ(pa3, hp.w);
        if (g + 2 < 32) {
          LDU(pa0, (g + 2) * 4 + 0); LDU(pa1, (g + 2) * 4 + 1);
          LDU(pa2, (g + 2) * 4 + 2); LDU(pa3, (g + 2) * 4 + 3);
        }
      }
      {
        const int g = 2 * g2 + 1;
        uint4 hp = *(const uint4*)&h_pk[g << 2];
        DOTQ(pb0, hp.x);
        DOTQ(pb1, hp.y);
        DOTQ(pb2, hp.z);
        DOTQ(pb3, hp.w);
        if (g + 2 < 32) {
          LDU(pb0, (g + 2) * 4 + 0); LDU(pb1, (g + 2) * 4 + 1);
          LDU(pb2, (g + 2) * 4 + 2); LDU(pb3, (g + 2) * 4 + 3);
        }
      }
    }

    float iG = sigm(z.x), fG = sigm(z.y), gG = tanh_fast(z.z), oG = sigm(z.w);
    c_ = fG * c_ + iG * gG;
    h_ = oG * tanh_fast(c_);
    __syncthreads();  // all h_pk reads of this step done
    ((half_t*)h_pk)[j] = (half_t)h_;
    if (WRITE_H) {
      size_t oi = ((((size_t)b << 10) + t) << 9) + dir * 256 + j;
      if (H_BF16)
        ((__hip_bfloat16*)hout)[oi] = __float2bfloat16(h_);
      else
        ((float*)hout)[oi] = h_;
    } else {
      float v = h_ * wdj;
#pragma unroll
      for (int o = 32; o > 0; o >>= 1) v += __shfl_down(v, o);
      if ((j & 63) == 0) red[j >> 6] = v;
    }
    __syncthreads();  // h_pk + red visible
    if (!WRITE_H && j == 0)
      atomicAdd(out + ((size_t)b << 10) + t,
                (red[0] + red[1]) + (red[2] + red[3]));
  }
  carry[((size_t)(dir * 2 + 0) * B_ + b) * 256 + j] = h_;
  carry[((size_t)(dir * 2 + 1) * B_ + b) * 256 + j] = c_;
#undef LDU
#undef DOTQ
}

extern "C" void kernel_launch(void* const* d_in, const int* in_sizes, int n_in,
                              void* d_out, int out_size, void* d_ws, size_t ws_size,
                              hipStream_t stream) {
  const float* x   = (const float*)d_in[0];
  const float* W0f = (const float*)d_in[1];
  const float* U0f = (const float*)d_in[2];
  const float* b0f = (const float*)d_in[3];
  const float* W0b = (const float*)d_in[4];
  const float* U0b = (const float*)d_in[5];
  const float* b0b = (const float*)d_in[6];
  const float* W1f = (const float*)d_in[7];
  const float* U1f = (const float*)d_in[8];
  const float* b1f = (const float*)d_in[9];
  const float* W1b = (const float*)d_in[10];
  const float* U1b = (const float*)d_in[11];
  const float* b1b = (const float*)d_in[12];
  const float* Wd  = (const float*)d_in[13];
  const float* bd  = (const float*)d_in[14];
  float* out = (float*)d_out;
  char* ws = (char*)d_ws;

  const size_t H0F_BYTES = (size_t)B_ * T_ * 512 * 4;    // 128 MiB (f32)
  const size_t UPK_BYTES = (size_t)128 * 1024 * 4;       // 512 KiB (f16 pairs)
  const size_t WP0_BYTES = (size_t)64 * 1024 * 4;        // 256 KiB
  const size_t WP1_BYTES = (size_t)512 * 1024 * 4;       // 2 MiB
  const size_t BP_BYTES  = 1024 * 4;
  const size_t REPACK = 4 * UPK_BYTES + 2 * WP0_BYTES + 2 * WP1_BYTES + 4 * BP_BYTES;
  const size_t CARRY_BYTES = (size_t)2 * 2 * B_ * 256 * 4;  // 512 KiB

  int h0bf16 = -1, Tc = 0;
  for (int prec = 0; prec < 2 && h0bf16 < 0; ++prec) {
    size_t h0b = prec ? (H0F_BYTES / 2) : H0F_BYTES;
    for (int tc = 128; tc >= 64; tc >>= 1) {
      size_t xpb = (size_t)2 * B_ * tc * 1024 * 4;
      if (h0b + REPACK + CARRY_BYTES + xpb <= ws_size) {
        h0bf16 = prec;
        Tc = tc;
        break;
      }
    }
  }
  if (h0bf16 < 0) {
    float v = 1000.f + (float)(ws_size >> 20);
    diag_out<<<(out_size + 255) / 256, 256, 0, stream>>>(out, out_size, v);
    return;
  }

  size_t h0b = h0bf16 ? (H0F_BYTES / 2) : H0F_BYTES;
  size_t off = 0;
  void*     h0   = (void*)(ws + off); off += h0b;
  unsigned* Up00 = (unsigned*)(ws + off); off += UPK_BYTES;
  unsigned* Up01 = (unsigned*)(ws + off); off += UPK_BYTES;
  unsigned* Up10 = (unsigned*)(ws + off); off += UPK_BYTES;
  unsigned* Up11 = (unsigned*)(ws + off); off += UPK_BYTES;
  float* Wp0f = (float*)(ws + off); off += WP0_BYTES;
  float* Wp0b = (float*)(ws + off); off += WP0_BYTES;
  float* Wp1f = (float*)(ws + off); off += WP1_BYTES;
  float* Wp1b = (float*)(ws + off); off += WP1_BYTES;
  float* bp0f = (float*)(ws + off); off += BP_BYTES;
  float* bp0b = (float*)(ws + off); off += BP_BYTES;
  float* bp1f = (float*)(ws + off); off += BP_BYTES;
  float* bp1b = (float*)(ws + off); off += BP_BYTES;
  float* carry = (float*)(ws + off); off += CARRY_BYTES;
  float* xpc  = (float*)(ws + off);

  // --- weight/bias repacking ---
  pack_u_f16<<<512, 256, 0, stream>>>(U0f, Up00);
  pack_u_f16<<<512, 256, 0, stream>>>(U0b, Up01);
  pack_u_f16<<<512, 256, 0, stream>>>(U1f, Up10);
  pack_u_f16<<<512, 256, 0, stream>>>(U1b, Up11);
  permute_cols<<<256, 256, 0, stream>>>(W0f, Wp0f, 64);
  permute_cols<<<256, 256, 0, stream>>>(W0b, Wp0b, 64);
  permute_cols<<<2048, 256, 0, stream>>>(W1f, Wp1f, 512);
  permute_cols<<<2048, 256, 0, stream>>>(W1b, Wp1b, 512);
  permute_cols<<<4, 256, 0, stream>>>(b0f, bp0f, 1);
  permute_cols<<<4, 256, 0, stream>>>(b0b, bp0b, 1);
  permute_cols<<<4, 256, 0, stream>>>(b1f, bp1f, 1);
  permute_cols<<<4, 256, 0, stream>>>(b1b, bp1b, 1);

  const int nch = T_ / Tc;
  const dim3 ggrid((Tc / 64) * 16, B_, 2);

  // ---- layer 0: x -> h0 ----
  for (int ci = 0; ci < nch; ++ci) {
    int s0c = ci * Tc;
    proj_gemm_chunk<0><<<ggrid, 256, 0, stream>>>(x, Wp0f, Wp0b, bp0f, bp0b,
                                                  xpc, 64, s0c, Tc);
    if (h0bf16)
      lstm_scan2<1, 1><<<128, 256, 0, stream>>>(xpc, Up00, Up01, carry, s0c, Tc,
                                                h0, nullptr, nullptr);
    else
      lstm_scan2<1, 0><<<128, 256, 0, stream>>>(xpc, Up00, Up01, carry, s0c, Tc,
                                                h0, nullptr, nullptr);
  }

  // ---- layer 1: h0 -> out (fused dense head) ----
  init_out<<<(out_size + 255) / 256, 256, 0, stream>>>(out, bd, out_size);
  for (int ci = 0; ci < nch; ++ci) {
    int s0c = ci * Tc;
    if (h0bf16)
      proj_gemm_chunk<1><<<ggrid, 256, 0, stream>>>(h0, Wp1f, Wp1b, bp1f, bp1b,
                                                    xpc, 512, s0c, Tc);
    else
      proj_gemm_chunk<0><<<ggrid, 256, 0, stream>>>(h0, Wp1f, Wp1b, bp1f, bp1b,
                                                    xpc, 512, s0c, Tc);
    lstm_scan2<0, 0><<<128, 256, 0, stream>>>(xpc, Up10, Up11, carry, s0c, Tc,
                                              nullptr, Wd, out);
  }
}

// Round 5
// 7491.560 us; speedup vs baseline: 2.4749x; 1.2741x over previous
//
#include <hip/hip_runtime.h>
#include <hip/hip_bf16.h>
#include <cstdint>
#include <cstddef>

#define B_ 64
#define T_ 1024

typedef _Float16 half_t;
typedef __attribute__((ext_vector_type(8))) _Float16 half8;
typedef __attribute__((ext_vector_type(4))) float f32x4;
typedef __attribute__((ext_vector_type(8))) unsigned short ushort8;

__device__ __forceinline__ float sigm(float x) { return 1.f / (1.f + __expf(-x)); }
__device__ __forceinline__ float tanh_fast(float x) {
  float e = __expf(2.f * x);
  return 1.f - 2.f / (e + 1.f);
}

// Permute columns into gate-interleaved order: dst[k][hc*4+g] = src[k][g*256+hc]
__global__ __launch_bounds__(256) void permute_cols(const float* __restrict__ src,
                                                    float* __restrict__ dst, int K) {
  int idx = blockIdx.x * 256 + threadIdx.x;
  if (idx >= K * 1024) return;
  int n = idx & 1023;
  size_t k = (size_t)(idx >> 10);
  dst[idx] = src[(k << 10) + ((size_t)(n & 3) << 8) + (n >> 2)];
}

// U [256][1024] (gate-blocked) -> MFMA B-fragment order, f16:
// dst flat [wgc(8)][w(4)][n(2)][s(8)][lane(64)][8]
// value = U[k = s*32 + (lane>>4)*8 + j][col' = wgc*128 + w*32 + n*16 + (lane&15)]
// where col' is gate-interleaved (col' = hc*4+g  <->  source col g*256+hc).
__global__ __launch_bounds__(256) void pack_u_mfma(const float* __restrict__ src,
                                                   half_t* __restrict__ dst) {
  int tid = blockIdx.x * 256 + threadIdx.x;  // 32768 lines
  int l = tid & 63;
  int s = (tid >> 6) & 7;
  int n = (tid >> 9) & 1;
  int w = (tid >> 10) & 3;
  int wgc = (tid >> 12) & 7;
  int col = wgc * 128 + w * 32 + n * 16 + (l & 15);
  int hc = col >> 2, g = col & 3;
  int k0 = s * 32 + (l >> 4) * 8;
  half8 v;
#pragma unroll
  for (int j = 0; j < 8; ++j)
    v[j] = (half_t)src[(size_t)(k0 + j) * 1024 + (g << 8) + hc];
  *(half8*)(dst + (size_t)tid * 8) = v;
}

__global__ __launch_bounds__(256) void zero_i32(int* __restrict__ p, int n) {
  int i = blockIdx.x * 256 + threadIdx.x;
  if (i < n) p[i] = 0;
}

__global__ __launch_bounds__(256) void init_out(float* __restrict__ out,
                                                const float* __restrict__ bd, int n) {
  int i = blockIdx.x * 256 + threadIdx.x;
  if (i < n) out[i] = bd[0];
}

__global__ __launch_bounds__(256) void diag_out(float* __restrict__ out, int n, float v) {
  int i = blockIdx.x * 256 + threadIdx.x;
  if (i < n) out[i] = (i == 0) ? v : 0.f;
}

// xp[dir][b][sl][1024] = A[b][t(sl)][:] @ Wperm[dir] + biasperm[dir]
template <int A_BF16>
__global__ __launch_bounds__(256) void proj_gemm_chunk(
    const void* __restrict__ Av,
    const float* __restrict__ Wf, const float* __restrict__ Wb,
    const float* __restrict__ bf_, const float* __restrict__ bb_,
    float* __restrict__ xp, int K, int s0, int Tc) {
  const int dir = blockIdx.z;
  const float* W = dir ? Wb : Wf;
  const float* bs = dir ? bb_ : bf_;
  const int b = blockIdx.y;
  const int tt = blockIdx.x >> 4;
  const int nt = blockIdx.x & 15;
  const int t0 = (dir ? (T_ - s0 - Tc) : s0) + (tt << 6);
  const int n0 = nt << 6;
  const int tid = threadIdx.x;
  const int tx = tid & 15, ty = tid >> 4;

  __shared__ __align__(16) float As[64][36];
  __shared__ __align__(16) float Bs[32][68];

  float acc[4][4];
#pragma unroll
  for (int i = 0; i < 4; i++)
#pragma unroll
    for (int j = 0; j < 4; j++) acc[i][j] = 0.f;

  const int r = tid >> 2;
  const int kc = (tid & 3) * 8;

  for (int k0 = 0; k0 < K; k0 += 32) {
    if (A_BF16) {
      const unsigned short* Ar = (const unsigned short*)Av +
          ((size_t)b * T_ + t0 + r) * K + k0 + kc;
      ushort8 v = *(const ushort8*)Ar;
#pragma unroll
      for (int jj = 0; jj < 8; jj++)
        As[r][kc + jj] = __uint_as_float(((unsigned)v[jj]) << 16);
    } else {
      const float* Ar = (const float*)Av + ((size_t)b * T_ + t0 + r) * K + k0 + kc;
      *(float4*)&As[r][kc] = *(const float4*)Ar;
      *(float4*)&As[r][kc + 4] = *(const float4*)(Ar + 4);
    }
#pragma unroll
    for (int u = 0; u < 2; u++) {
      int f = tid * 2 + u;
      int kk = f >> 4;
      int cc = f & 15;
      *(float4*)&Bs[kk][cc * 4] =
          *(const float4*)(W + (size_t)(k0 + kk) * 1024 + n0 + cc * 4);
    }
    __syncthreads();
#pragma unroll
    for (int kk = 0; kk < 32; ++kk) {
      float4 bq = *(const float4*)&Bs[kk][tx * 4];
      float a0 = As[ty * 4 + 0][kk];
      float a1 = As[ty * 4 + 1][kk];
      float a2 = As[ty * 4 + 2][kk];
      float a3 = As[ty * 4 + 3][kk];
      acc[0][0] += a0 * bq.x; acc[0][1] += a0 * bq.y; acc[0][2] += a0 * bq.z; acc[0][3] += a0 * bq.w;
      acc[1][0] += a1 * bq.x; acc[1][1] += a1 * bq.y; acc[1][2] += a1 * bq.z; acc[1][3] += a1 * bq.w;
      acc[2][0] += a2 * bq.x; acc[2][1] += a2 * bq.y; acc[2][2] += a2 * bq.z; acc[2][3] += a2 * bq.w;
      acc[3][0] += a3 * bq.x; acc[3][1] += a3 * bq.y; acc[3][2] += a3 * bq.z; acc[3][3] += a3 * bq.w;
    }
    __syncthreads();
  }
  float4 bv = *(const float4*)(bs + n0 + tx * 4);
#pragma unroll
  for (int i = 0; i < 4; i++) {
    int t = t0 + ty * 4 + i;
    int sl = dir ? (T_ - 1 - t - s0) : (t - s0);
    float4 o;
    o.x = acc[i][0] + bv.x;
    o.y = acc[i][1] + bv.y;
    o.z = acc[i][2] + bv.z;
    o.w = acc[i][3] + bv.w;
    *(float4*)(xp + ((((size_t)dir * B_ + b) * Tc + sl) << 10) + n0 + tx * 4) = o;
  }
}

// MFMA scan. Grid = 64 WGs: blk = unit*8 + wgc; unit = (bgroup<<1)|dir.
// Each unit = (dir, 16 batches); 8 WGs split the 1024 gate-cols (128 each).
// U held in VGPRs (f16 fragments); h exchanged per step through agent-scope
// stores + per-unit spin barrier; A (h) staged in LDS in MFMA A-layout.
// WRITE_H=1: layer 0, write h to hout ([B][T][512]).
// WRITE_H=0: layer 1, fused dense head: atomicAdd(out[b*T+t], sum h*Wd).
template <int WRITE_H, int H_BF16>
__global__ __launch_bounds__(256, 1) void lstm_scan_mfma(
    const float* __restrict__ xp,
    const half_t* __restrict__ Upk_f, const half_t* __restrict__ Upk_b,
    float* __restrict__ carry_c,
    unsigned short* __restrict__ exch,   // [unit][slot2][4096] f16 (A-layout)
    int* __restrict__ flags,             // [unit][128]
    int s0, int Tc,
    void* __restrict__ hout,
    const float* __restrict__ Wd, float* __restrict__ out) {
  const int blk = blockIdx.x;
  const int unit = blk >> 3;
  const int wgc = blk & 7;
  const int dir = unit & 1;
  const int b0u = (unit >> 1) * 16;
  const int tid = threadIdx.x;
  const int l = tid & 63;
  const int w = tid >> 6;

  __shared__ __align__(16) half_t A_lds[4096];  // [kchunk32][b16][8]
  __shared__ float red_sm[64];                  // [wave][batch16]

  const half_t* Upk = dir ? Upk_b : Upk_f;
  half8 U[2][8];
  {
    const half_t* up = Upk + (size_t)(wgc * 4 + w) * 8192;
#pragma unroll
    for (int n = 0; n < 2; ++n)
#pragma unroll
      for (int s = 0; s < 8; ++s)
        U[n][s] = *(const half8*)(up + ((size_t)(n * 8 + s) * 64 + l) * 8);
  }

  const int b_lane = 4 * (l >> 4) + (l & 3);
  const int hcb = wgc * 32 + w * 8 + ((l >> 2) & 3);  // + n*4
  float cst[2];
#pragma unroll
  for (int n = 0; n < 2; ++n) {
    cst[n] = (s0 == 0) ? 0.f
        : carry_c[((size_t)dir * B_ + b0u + b_lane) * 256 + hcb + n * 4];
  }
  float wdl[2];
  if (!WRITE_H) {
#pragma unroll
    for (int n = 0; n < 2; ++n) wdl[n] = Wd[dir * 256 + hcb + n * 4];
  }

  unsigned short* exch_u = exch + (size_t)unit * 2 * 4096;
  int* flag_u = flags + unit * 128;

  if (s0 == 0) {
    ((uint4*)A_lds)[tid] = make_uint4(0, 0, 0, 0);
    ((uint4*)A_lds)[256 + tid] = make_uint4(0, 0, 0, 0);
  } else {
    const unsigned long long* ex = (const unsigned long long*)(exch_u + 4096);
    unsigned long long d[4];
#pragma unroll
    for (int i = 0; i < 4; ++i)
      d[i] = __hip_atomic_load(ex + tid * 4 + i, __ATOMIC_RELAXED,
                               __HIP_MEMORY_SCOPE_AGENT);
#pragma unroll
    for (int i = 0; i < 4; ++i)
      ((unsigned long long*)A_lds)[tid * 4 + i] = d[i];
  }
  __syncthreads();

  const int colb = wgc * 128 + w * 32 + (l & 15);  // + n*16
  const float* xpu = xp + ((size_t)(dir * B_ + b0u) * Tc) * 1024;

  for (int sl = 0; sl < Tc; ++sl) {
    const int s = s0 + sl;
    const int t = dir ? (T_ - 1 - s) : s;

    // acc init = xp (C-operand of MFMA); batch = 4*(l>>4)+r, col = colb+n*16
    f32x4 acc[2];
#pragma unroll
    for (int n = 0; n < 2; ++n)
#pragma unroll
      for (int r = 0; r < 4; ++r)
        acc[n][r] = xpu[((size_t)(4 * (l >> 4) + r) * Tc + sl) * 1024 + colb + n * 16];

    // A fragments: lane l = h[b = l&15][k = s*32 + (l>>4)*8 + j]
    half8 a[8];
#pragma unroll
    for (int sK = 0; sK < 8; ++sK)
      a[sK] = *(const half8*)&A_lds[((sK * 4 + (l >> 4)) * 16 + (l & 15)) * 8];

#pragma unroll
    for (int sK = 0; sK < 8; ++sK) {
      acc[0] = __builtin_amdgcn_mfma_f32_16x16x32_f16(a[sK], U[0][sK], acc[0], 0, 0, 0);
      acc[1] = __builtin_amdgcn_mfma_f32_16x16x32_f16(a[sK], U[1][sK], acc[1], 0, 0, 0);
    }

    float vhead = 0.f;
#pragma unroll
    for (int n = 0; n < 2; ++n) {
      // 4x4 transpose across lane group (g = l&3) and regs: u[r] = Z[r][g]
      float v0 = acc[n][0], v1 = acc[n][1], v2 = acc[n][2], v3 = acc[n][3];
      float x0 = __shfl_xor(v1, 1), x1 = __shfl_xor(v0, 1);
      float x2 = __shfl_xor(v3, 1), x3 = __shfl_xor(v2, 1);
      float a0 = (l & 1) ? x0 : v0;
      float a1 = (l & 1) ? v1 : x1;
      float a2 = (l & 1) ? x2 : v2;
      float a3 = (l & 1) ? v3 : x3;
      float y0 = __shfl_xor(a2, 2), y1 = __shfl_xor(a3, 2);
      float y2 = __shfl_xor(a0, 2), y3 = __shfl_xor(a1, 2);
      float u0 = (l & 2) ? y0 : a0;
      float u1 = (l & 2) ? y1 : a1;
      float u2 = (l & 2) ? a2 : y2;
      float u3 = (l & 2) ? a3 : y3;

      float iG = sigm(u0), fG = sigm(u1), gG = tanh_fast(u2), oG = sigm(u3);
      float cn = fG * cst[n] + iG * gG;
      cst[n] = cn;
      float h = oG * tanh_fast(cn);

      const int hc = hcb + n * 4;
      if (WRITE_H) {
        size_t ho = ((size_t)(b0u + b_lane) * T_ + t) * 512 + dir * 256 + hc;
        if (H_BF16)
          ((__hip_bfloat16*)hout)[ho] = __float2bfloat16(h);
        else
          ((float*)hout)[ho] = h;
      } else {
        vhead += h * wdl[n];
      }

      half_t hh = (half_t)h;
      unsigned short hu = __builtin_bit_cast(unsigned short, hh);
      __hip_atomic_store(
          exch_u + (sl & 1) * 4096 + ((hc >> 3) * 16 + b_lane) * 8 + (hc & 7),
          hu, __ATOMIC_RELAXED, __HIP_MEMORY_SCOPE_AGENT);
      if (sl == Tc - 1)
        carry_c[((size_t)dir * B_ + b0u + b_lane) * 256 + hc] = cn;
    }

    if (!WRITE_H) {
      // reduce the 4 hc-groups (lane bits 2-3) -> per-(wave,batch) partial
      vhead += __shfl_xor(vhead, 4);
      vhead += __shfl_xor(vhead, 8);
      if ((l & 12) == 0) red_sm[w * 16 + b_lane] = vhead;
    }

    asm volatile("s_waitcnt vmcnt(0)" ::: "memory");
    __syncthreads();
    if (tid == 0)
      __hip_atomic_fetch_add(flag_u + sl, 1, __ATOMIC_RELAXED,
                             __HIP_MEMORY_SCOPE_AGENT);
    if (!WRITE_H && tid < 16) {
      float sum = (red_sm[tid] + red_sm[16 + tid]) +
                  (red_sm[32 + tid] + red_sm[48 + tid]);
      atomicAdd(out + ((size_t)(b0u + tid) << 10) + t, sum);
    }
    if (sl + 1 < Tc) {
      if (tid == 0) {
        while (__hip_atomic_load(flag_u + sl, __ATOMIC_RELAXED,
                                 __HIP_MEMORY_SCOPE_AGENT) < 8)
          __builtin_amdgcn_s_sleep(2);
      }
      __syncthreads();
      const unsigned long long* ex =
          (const unsigned long long*)(exch_u + (sl & 1) * 4096);
      unsigned long long d[4];
#pragma unroll
      for (int i = 0; i < 4; ++i)
        d[i] = __hip_atomic_load(ex + tid * 4 + i, __ATOMIC_RELAXED,
                                 __HIP_MEMORY_SCOPE_AGENT);
#pragma unroll
      for (int i = 0; i < 4; ++i)
        ((unsigned long long*)A_lds)[tid * 4 + i] = d[i];
      __syncthreads();
    }
  }
}

extern "C" void kernel_launch(void* const* d_in, const int* in_sizes, int n_in,
                              void* d_out, int out_size, void* d_ws, size_t ws_size,
                              hipStream_t stream) {
  const float* x   = (const float*)d_in[0];
  const float* W0f = (const float*)d_in[1];
  const float* U0f = (const float*)d_in[2];
  const float* b0f = (const float*)d_in[3];
  const float* W0b = (const float*)d_in[4];
  const float* U0b = (const float*)d_in[5];
  const float* b0b = (const float*)d_in[6];
  const float* W1f = (const float*)d_in[7];
  const float* U1f = (const float*)d_in[8];
  const float* b1f = (const float*)d_in[9];
  const float* W1b = (const float*)d_in[10];
  const float* U1b = (const float*)d_in[11];
  const float* b1b = (const float*)d_in[12];
  const float* Wd  = (const float*)d_in[13];
  const float* bd  = (const float*)d_in[14];
  float* out = (float*)d_out;
  char* ws = (char*)d_ws;

  const size_t H0F_BYTES = (size_t)B_ * T_ * 512 * 4;     // 128 MiB
  const size_t UPK_BYTES = (size_t)262144 * 2;            // 512 KiB (f16 frags)
  const size_t WP0_BYTES = (size_t)64 * 1024 * 4;
  const size_t WP1_BYTES = (size_t)512 * 1024 * 4;
  const size_t BP_BYTES  = 1024 * 4;
  const size_t CC_BYTES  = (size_t)2 * B_ * 256 * 4;      // 128 KiB
  const size_t EX_BYTES  = (size_t)8 * 2 * 4096 * 2;      // 128 KiB
  const size_t FL_BYTES  = 8 * 128 * 4;                   // 4 KiB
  const size_t REPACK = 4 * UPK_BYTES + 2 * WP0_BYTES + 2 * WP1_BYTES +
                        4 * BP_BYTES + CC_BYTES + EX_BYTES + FL_BYTES + 1024;

  int h0bf16 = -1, Tc = 0;
  for (int prec = 0; prec < 2 && h0bf16 < 0; ++prec) {
    size_t h0b = prec ? (H0F_BYTES / 2) : H0F_BYTES;
    for (int tc = 128; tc >= 64; tc >>= 1) {
      size_t xpb = (size_t)2 * B_ * tc * 1024 * 4;
      if (h0b + REPACK + xpb <= ws_size) {
        h0bf16 = prec;
        Tc = tc;
        break;
      }
    }
  }
  if (h0bf16 < 0) {
    float v = 1000.f + (float)(ws_size >> 20);
    diag_out<<<(out_size + 255) / 256, 256, 0, stream>>>(out, out_size, v);
    return;
  }

  size_t h0b = h0bf16 ? (H0F_BYTES / 2) : H0F_BYTES;
  size_t off = 0;
  void*   h0   = (void*)(ws + off); off += h0b;
  half_t* Up00 = (half_t*)(ws + off); off += UPK_BYTES;
  half_t* Up01 = (half_t*)(ws + off); off += UPK_BYTES;
  half_t* Up10 = (half_t*)(ws + off); off += UPK_BYTES;
  half_t* Up11 = (half_t*)(ws + off); off += UPK_BYTES;
  float* Wp0f = (float*)(ws + off); off += WP0_BYTES;
  float* Wp0b = (float*)(ws + off); off += WP0_BYTES;
  float* Wp1f = (float*)(ws + off); off += WP1_BYTES;
  float* Wp1b = (float*)(ws + off); off += WP1_BYTES;
  float* bp0f = (float*)(ws + off); off += BP_BYTES;
  float* bp0b = (float*)(ws + off); off += BP_BYTES;
  float* bp1f = (float*)(ws + off); off += BP_BYTES;
  float* bp1b = (float*)(ws + off); off += BP_BYTES;
  float* carry_c = (float*)(ws + off); off += CC_BYTES;
  unsigned short* exch = (unsigned short*)(ws + off); off += EX_BYTES;
  int* flags = (int*)(ws + off); off += FL_BYTES;
  off = (off + 255) & ~(size_t)255;
  float* xpc = (float*)(ws + off);

  // --- weight/bias repacking ---
  pack_u_mfma<<<128, 256, 0, stream>>>(U0f, Up00);
  pack_u_mfma<<<128, 256, 0, stream>>>(U0b, Up01);
  pack_u_mfma<<<128, 256, 0, stream>>>(U1f, Up10);
  pack_u_mfma<<<128, 256, 0, stream>>>(U1b, Up11);
  permute_cols<<<256, 256, 0, stream>>>(W0f, Wp0f, 64);
  permute_cols<<<256, 256, 0, stream>>>(W0b, Wp0b, 64);
  permute_cols<<<2048, 256, 0, stream>>>(W1f, Wp1f, 512);
  permute_cols<<<2048, 256, 0, stream>>>(W1b, Wp1b, 512);
  permute_cols<<<4, 256, 0, stream>>>(b0f, bp0f, 1);
  permute_cols<<<4, 256, 0, stream>>>(b0b, bp0b, 1);
  permute_cols<<<4, 256, 0, stream>>>(b1f, bp1f, 1);
  permute_cols<<<4, 256, 0, stream>>>(b1b, bp1b, 1);

  const int nch = T_ / Tc;
  const dim3 ggrid((Tc / 64) * 16, B_, 2);

  // ---- layer 0: x -> h0 ----
  for (int ci = 0; ci < nch; ++ci) {
    int s0c = ci * Tc;
    proj_gemm_chunk<0><<<ggrid, 256, 0, stream>>>(x, Wp0f, Wp0b, bp0f, bp0b,
                                                  xpc, 64, s0c, Tc);
    zero_i32<<<4, 256, 0, stream>>>(flags, 1024);
    if (h0bf16)
      lstm_scan_mfma<1, 1><<<64, 256, 0, stream>>>(xpc, Up00, Up01, carry_c, exch,
                                                   flags, s0c, Tc, h0, nullptr, nullptr);
    else
      lstm_scan_mfma<1, 0><<<64, 256, 0, stream>>>(xpc, Up00, Up01, carry_c, exch,
                                                   flags, s0c, Tc, h0, nullptr, nullptr);
  }

  // ---- layer 1: h0 -> out (fused dense head; h0 is read-only here) ----
  init_out<<<(out_size + 255) / 256, 256, 0, stream>>>(out, bd, out_size);
  for (int ci = 0; ci < nch; ++ci) {
    int s0c = ci * Tc;
    if (h0bf16)
      proj_gemm_chunk<1><<<ggrid, 256, 0, stream>>>(h0, Wp1f, Wp1b, bp1f, bp1b,
                                                    xpc, 512, s0c, Tc);
    else
      proj_gemm_chunk<0><<<ggrid, 256, 0, stream>>>(h0, Wp1f, Wp1b, bp1f, bp1b,
                                                    xpc, 512, s0c, Tc);
    zero_i32<<<4, 256, 0, stream>>>(flags, 1024);
    lstm_scan_mfma<0, 0><<<64, 256, 0, stream>>>(xpc, Up10, Up11, carry_c, exch,
                                                 flags, s0c, Tc, nullptr, Wd, out);
  }
}